// Round 19
// baseline (321.398 us; speedup 1.0000x reference)
//
#include <hip/hip_runtime.h>

// ---------------------------------------------------------------------------
// LinearAggActor R18 (= R16 revert, session best 253us):
//  - math (verified R2-R16): z0 = t2@(w3@w1)+b3@w1 (16-dim); z_k = A^k z0;
//    logits = cvec + sum_k relu(relu(z_k+b1)@w2+b2) @ M_k ; softmax.
//  - R17 post-mortem: __launch_bounds__(256,4) on proj_k forced VGPR=64 ->
//    104MB scratch SPILL traffic, 88-145us. REVERTED to unbounded (VGPR=256,
//    2 blocks/CU, ~50us): fat-math kernels here need their registers; both
//    directions (unbounded=50us, bounded=spill) now measured.
//  - R16 (verified): hop agg = 4 nodes/wave, two uint4 -> 16 float4 gathers
//    in flight; csrp permutation pos=((j&3)<<4)|(j>>2).
//  - build (R10-15): binfill multisplit + setup on idle CUs; csr2 low-VGPR
//    -> permuted padded ushort csrp + degs (+dense tail); sentinel row n.
// ---------------------------------------------------------------------------

#define NB2MAX 400   // bins of 128 dsts: supports n <= 51200
#define NBLK   256   // binfill blocks
#define CAP2   32    // LDS staging per bin
#define CAPC   48    // per-(bin,block) cell capacity (mean 16, +8 sigma)
#define CAPB   6144  // per-bin dense CSR region (overflow tails only)
#define OVCAP  1024  // per-bin overflow region (statistically unused)
#define LCAP   6144  // csr2 per-bin LDS capacity (mean 4096, +32 sigma)
#define CAPN   64    // padded slots per node (mean 32, +5.7 sigma)

// blocks [0,NBLK): multisplit into private (bin,block) cells; packed
// (dloc<<16|src); LDS cursors; no global atomics on the hot path.
// blocks [NBLK, NBLK+9): setup role (R10-verified).
__global__ __launch_bounds__(1024) void binfill_k(
    const int* __restrict__ src, const int* __restrict__ dst, int E, int n,
    int* __restrict__ gcur, int* __restrict__ ovbuf,
    int* __restrict__ bins, int* __restrict__ cnts,
    const float* __restrict__ w1, const float* __restrict__ w3,
    const float* __restrict__ b3, const float* __restrict__ fc1w,
    const float* __restrict__ fc1b, const float* __restrict__ fc2w,
    const float* __restrict__ fc2b,
    float* __restrict__ M, float* __restrict__ cvec,
    float* __restrict__ W31, float* __restrict__ c31) {
    __shared__ int lbuf[NB2MAX * CAP2];
    __shared__ int lcnt[NB2MAX];
    __shared__ int lflush[NB2MAX];
    int tid = threadIdx.x;
    int NB = (n + 127) >> 7;

    if ((int)blockIdx.x >= NBLK) {
        // ---------------- setup role ----------------
        float* fl = (float*)lbuf;   // LDS reuse
        int s = (int)blockIdx.x - NBLK;
        if (s == 0) {
            if (tid < 256) {
                int i = tid >> 4, j = tid & 15;
                float a = 0.f;
                for (int g = 0; g < 64; g++) a += w3[i * 64 + g] * w1[g * 16 + j];
                W31[tid] = a;
            } else if (tid < 272) {
                int j = tid - 256;
                float a = 0.f;
                for (int g = 0; g < 64; g++) a += b3[g] * w1[g * 16 + j];
                c31[j] = a;
            } else if (tid >= 320 && tid < 384) {
                int h = tid - 320;
                float a = 0.f;
                for (int r = 0; r < 512; r++) a += b3[r & 63] * fc1w[r * 64 + h];
                fl[h] = a;   // u[h]
            }
            __syncthreads();
            if (tid < 8) {
                float a = fc2b[tid];
                for (int h = 0; h < 64; h++) a += (fc1b[h] + fl[h]) * fc2w[h * 8 + tid];
                cvec[tid] = a;
            }
        } else {
            int k = s - 1;
            {   // Q_k: one elem per thread
                int i = tid >> 6, h = tid & 63;
                float a = 0.f;
                const float* f1 = fc1w + (size_t)(k * 64) * 64 + h;
                for (int g = 0; g < 64; g++) a += w3[i * 64 + g] * f1[g * 64];
                fl[i * 64 + h] = a;
            }
            __syncthreads();
            if (tid < 128) {
                int i = tid >> 3, j = tid & 7;
                float a = 0.f;
                for (int h = 0; h < 64; h++) a += fl[i * 64 + h] * fc2w[h * 8 + j];
                M[k * 128 + i * 8 + j] = a;
            }
        }
        return;
    }

    // ---------------- binfill role ----------------
    for (int b = tid; b < NB; b += 1024) { lcnt[b] = 0; lflush[b] = 0; }
    __syncthreads();
    int blk = blockIdx.x;
    int chunk = (E + NBLK - 1) / NBLK;
    int beg = blk * chunk;
    int end = beg + chunk; if (end > E) end = E;
    for (int t0 = beg; t0 < end; t0 += 1024) {
        int e = t0 + tid;
        if (e < end) {
            int d = dst[e], s = src[e];
            if ((unsigned)d < (unsigned)n && (unsigned)s < (unsigned)n) {
                int b = d >> 7;
                int pk = ((d & 127) << 16) | s;
                int pos = atomicAdd(&lcnt[b], 1);
                if (pos < CAP2) lbuf[b * CAP2 + pos] = pk;
                else {  // statistically never
                    int p = atomicAdd(&gcur[b], 1);
                    if (p < OVCAP) ovbuf[b * OVCAP + p] = pk;
                }
            }
        }
        __syncthreads();
        for (int b = tid; b < NB; b += 1024) {
            int cnt = lcnt[b]; if (cnt > CAP2) cnt = CAP2;
            int fl2 = lflush[b];
            size_t cell = ((size_t)b * NBLK + blk) * CAPC;
            int base = 0;
            while (cnt - base >= 16) {
                if (fl2 + 16 <= CAPC) {
                    int* dp = bins + cell + fl2;
                    #pragma unroll
                    for (int q = 0; q < 16; q++) dp[q] = lbuf[b * CAP2 + base + q];
                    fl2 += 16;
                } else {  // cell overflow (statistically never)
                    int p = atomicAdd(&gcur[b], 16);
                    for (int q = 0; q < 16; q++)
                        if (p + q < OVCAP) ovbuf[b * OVCAP + p + q] = lbuf[b * CAP2 + base + q];
                }
                base += 16;
            }
            int rem = cnt - base;
            if (base > 0)
                for (int q = 0; q < rem; q++) lbuf[b * CAP2 + q] = lbuf[b * CAP2 + base + q];
            lcnt[b] = rem; lflush[b] = fl2;
        }
        __syncthreads();
    }
    for (int b = tid; b < NB; b += 1024) {
        int cnt = lcnt[b]; if (cnt > CAP2) cnt = CAP2;
        int fl2 = lflush[b];
        size_t cell = ((size_t)b * NBLK + blk) * CAPC;
        if (fl2 + cnt <= CAPC) {
            for (int q = 0; q < cnt; q++) bins[cell + fl2 + q] = lbuf[b * CAP2 + q];
            fl2 += cnt;
        } else {
            int p = atomicAdd(&gcur[b], cnt);
            for (int q = 0; q < cnt; q++)
                if (p + q < OVCAP) ovbuf[b * OVCAP + p + q] = lbuf[b * CAP2 + q];
        }
        cnts[(size_t)blk * NB + b] = fl2;
    }
}

// per-bin counting sort -> permuted padded USHORT csrp + degs (+ dense tail
// csr/be for deg>64). One WG per bin; int-only, low VGPR.
// csrp permutation: sorted slot j -> pos ((j&3)<<4)|(j>>2): hop thread t
// owns slots {t, 4+t, ..., 60+t} = 16 contiguous ushorts = two uint4 loads.
__global__ __launch_bounds__(256) void csr2_k(
    const int* __restrict__ bins, const int* __restrict__ cnts,
    const int* __restrict__ gcur, const int* __restrict__ ovbuf,
    unsigned short* __restrict__ csrp, int* __restrict__ degs,
    int* __restrict__ csr, int2* __restrict__ be, int n) {
    __shared__ int hist[128], pref[128], cur[128];
    __shared__ int scnt[NBLK];
    __shared__ int lbuf[LCAP];
    __shared__ int sov;
    int tid = threadIdx.x;
    int NB = (n + 127) >> 7;
    int b = blockIdx.x;
    if (tid < 128) { hist[tid] = 0; cur[tid] = 0; }
    scnt[tid] = cnts[(size_t)tid * NB + b];
    if (tid == 0) {
        int g = gcur[b];
        sov = g < 0 ? 0 : (g > OVCAP ? OVCAP : g);
    }
    __syncthreads();
    {   // pass 1: histogram of dst-local
        int c = scnt[tid];
        size_t cell = ((size_t)b * NBLK + tid) * CAPC;
        for (int i = 0; i < c; i++) atomicAdd(&hist[bins[cell + i] >> 16], 1);
    }
    if (tid == 0)
        for (int i = 0; i < sov; i++) atomicAdd(&hist[ovbuf[b * OVCAP + i] >> 16], 1);
    __syncthreads();
    if (tid == 0) {
        int r = 0;
        for (int i = 0; i < 128; i++) { pref[i] = r; r += hist[i]; }
    }
    __syncthreads();
    {   // pass 2: place into LDS (bin-locally dense, sorted by dst)
        int c = scnt[tid];
        size_t cell = ((size_t)b * NBLK + tid) * CAPC;
        for (int i = 0; i < c; i++) {
            int pk = bins[cell + i];
            int dl = pk >> 16;
            int pos = pref[dl] + atomicAdd(&cur[dl], 1);
            if (pos < LCAP) lbuf[pos] = pk & 0xffff;
        }
    }
    if (tid == 0) {
        for (int i = 0; i < sov; i++) {
            int pk = ovbuf[b * OVCAP + i];
            int dl = pk >> 16;
            int pos = pref[dl] + atomicAdd(&cur[dl], 1);
            if (pos < LCAP) lbuf[pos] = pk & 0xffff;
        }
    }
    __syncthreads();
    // permuted padded ushort CSR; sentinel = n (zero row of z).
    for (int q = tid; q < 128 * CAPN; q += 256) {
        int dl = q >> 6, j = q & 63;
        int d = (b << 7) + dl;
        if (d >= n) break;
        int cnt = hist[dl];
        int v = (j < cnt) ? lbuf[pref[dl] + j] : n;
        int pos = ((j & 3) << 4) | (j >> 2);
        csrp[(size_t)d * CAPN + pos] = (unsigned short)v;
    }
    if (tid < 128) {
        int d = (b << 7) + tid;
        if (d < n) {
            int cnt = hist[tid];
            degs[d] = cnt;
            if (cnt > CAPN) {   // rare tail -> dense region + be (premult x4)
                int s0 = b * CAPB + pref[tid];
                be[d] = make_int2(s0 + CAPN, s0 + cnt);
                for (int j = CAPN; j < cnt; j++)
                    csr[s0 + j] = lbuf[pref[tid] + j] << 2;
            }
        }
    }
}

// proj (streamed x -> z0) + field0 (logits = cvec + f0); zero sentinel rows.
// NO launch_bounds: unbounded = VGPR 256, 2 blocks/CU, ~50us (R16 measured);
// bounding to (256,4) caused 104MB scratch spill and 88-145us (R17 measured).
__global__ void proj_k(
    const float* __restrict__ x, float* __restrict__ z0, float* __restrict__ z1,
    float* __restrict__ logits,
    const float* __restrict__ w1, const float* __restrict__ b1,
    const float* __restrict__ w2, const float* __restrict__ b2,
    const float* __restrict__ W31, const float* __restrict__ c31,
    const float* __restrict__ M0, const float* __restrict__ cvec, int n) {
    __shared__ float sw1[1024], sw2[256], sW[256], sM[128];
    __shared__ float sb1[16], sb2[16], sc[16], scv[8];
    int tid = threadIdx.x;
    for (int i = tid; i < 1024; i += 256) sw1[i] = w1[i];
    sw2[tid] = w2[tid & 255];
    sW[tid & 255] = W31[tid & 255];
    if (tid < 128) sM[tid] = M0[tid];
    if (tid < 16) { sb1[tid] = b1[tid]; sb2[tid] = b2[tid]; sc[tid] = c31[tid]; }
    if (tid < 8) scv[tid] = cvec[tid];
    __syncthreads();
    if (blockIdx.x == 0 && tid < 16) {   // zero sentinel row n of both bufs
        z0[(size_t)n * 16 + tid] = 0.f;
        z1[(size_t)n * 16 + tid] = 0.f;
    }
    int nid = blockIdx.x * 256 + tid;
    if (nid >= n) return;
    float t1[16];
    #pragma unroll
    for (int j = 0; j < 16; j++) t1[j] = sb1[j];
    const float4* xp = (const float4*)(x + (size_t)nid * 64);
    #pragma unroll
    for (int q = 0; q < 16; q++) {
        float4 v = xp[q];
        #pragma unroll
        for (int j = 0; j < 16; j++)
            t1[j] += v.x * sw1[(4 * q) * 16 + j] + v.y * sw1[(4 * q + 1) * 16 + j]
                   + v.z * sw1[(4 * q + 2) * 16 + j] + v.w * sw1[(4 * q + 3) * 16 + j];
    }
    #pragma unroll
    for (int j = 0; j < 16; j++) t1[j] = fmaxf(t1[j], 0.f);
    float t2[16];
    #pragma unroll
    for (int j = 0; j < 16; j++) {
        float a = sb2[j];
        #pragma unroll
        for (int i = 0; i < 16; i++) a += t1[i] * sw2[i * 16 + j];
        t2[j] = fmaxf(a, 0.f);
    }
    float z[16];
    #pragma unroll
    for (int j = 0; j < 16; j++) {
        float a = sc[j];
        #pragma unroll
        for (int i = 0; i < 16; i++) a += t2[i] * sW[i * 16 + j];
        z[j] = a;
    }
    float4* zo = (float4*)(z0 + (size_t)nid * 16);
    #pragma unroll
    for (int q = 0; q < 4; q++)
        zo[q] = make_float4(z[4 * q], z[4 * q + 1], z[4 * q + 2], z[4 * q + 3]);
    float h[16], f2[16];
    #pragma unroll
    for (int i = 0; i < 16; i++) h[i] = fmaxf(z[i] + sb1[i], 0.f);
    #pragma unroll
    for (int j = 0; j < 16; j++) {
        float a = sb2[j];
        #pragma unroll
        for (int i = 0; i < 16; i++) a += h[i] * sw2[i * 16 + j];
        f2[j] = fmaxf(a, 0.f);
    }
    float* lp = logits + (size_t)nid * 8;
    #pragma unroll
    for (int j = 0; j < 8; j++) {
        float l = scv[j];
        #pragma unroll
        for (int i = 0; i < 16; i++) l += f2[i] * sM[i * 8 + j];
        lp[j] = l;
    }
}

// One launch per hop. Blocks [0,FB): field(z_k) thread-per-node;
// blocks [FB,..): agg, 4 nodes/wave (16 lanes each = 4 slot-groups x 4 chans),
// two uint4 -> 16 round-indices -> 16 float4 gathers in flight per thread.
__global__ __launch_bounds__(256, 4) void hop_k(
    const float* __restrict__ zin, float* __restrict__ zout, float* __restrict__ logits,
    const unsigned short* __restrict__ csrp, const int* __restrict__ degs,
    const int2* __restrict__ be, const int* __restrict__ csr,
    const float* __restrict__ w2, const float* __restrict__ b1,
    const float* __restrict__ b2, const float* __restrict__ M, int n, int FB) {
    __shared__ float sw2[256], sM[128], sb1[16], sb2[16];
    int tid = threadIdx.x;
    if ((int)blockIdx.x < FB) {
        // ---- field role ----
        sw2[tid] = w2[tid];
        if (tid < 128) sM[tid] = M[tid];
        if (tid < 16) { sb1[tid] = b1[tid]; sb2[tid] = b2[tid]; }
        __syncthreads();
        int nid = blockIdx.x * 256 + tid;
        if (nid >= n) return;
        float h[16];
        const float4* zp = (const float4*)(zin + (size_t)nid * 16);
        #pragma unroll
        for (int q = 0; q < 4; q++) {
            float4 v = zp[q];
            h[4 * q] = v.x; h[4 * q + 1] = v.y; h[4 * q + 2] = v.z; h[4 * q + 3] = v.w;
        }
        #pragma unroll
        for (int i = 0; i < 16; i++) h[i] = fmaxf(h[i] + sb1[i], 0.f);
        float t2[16];
        #pragma unroll
        for (int j = 0; j < 16; j++) {
            float a = sb2[j];
            #pragma unroll
            for (int i = 0; i < 16; i++) a += h[i] * sw2[i * 16 + j];
            t2[j] = fmaxf(a, 0.f);
        }
        float* lp = logits + (size_t)nid * 8;
        #pragma unroll
        for (int j = 0; j < 8; j++) {
            float l = 0.f;
            #pragma unroll
            for (int i = 0; i < 16; i++) l += t2[i] * sM[i * 8 + j];
            lp[j] += l;
        }
        return;
    }
    // ---- agg role: 4 nodes per wave ----
    int wave = tid >> 6;
    int lane = tid & 63;
    int quarter = lane >> 4;              // which node of the 4
    int l16 = lane & 15;
    int t = l16 >> 2, c = l16 & 3;        // slot-group 0..3, channel 0..3
    int node = (((int)blockIdx.x - FB) * 4 + wave) * 4 + quarter;
    if (node >= n) return;
    int degi = degs[node];                // independent load, hidden
    // two 16B loads = 16 round-indices for this thread's slot-group
    const uint4* ip = (const uint4*)(csrp + ((size_t)node << 6));
    uint4 pa = ip[t * 2];
    uint4 pb = ip[t * 2 + 1];
    int r0 = pa.x & 0xffff, r1 = pa.x >> 16;
    int r2 = pa.y & 0xffff, r3 = pa.y >> 16;
    int r4 = pa.z & 0xffff, r5 = pa.z >> 16;
    int r6 = pa.w & 0xffff, r7 = pa.w >> 16;
    int r8 = pb.x & 0xffff, r9 = pb.x >> 16;
    int rA = pb.y & 0xffff, rB = pb.y >> 16;
    int rC = pb.z & 0xffff, rD = pb.z >> 16;
    int rE = pb.w & 0xffff, rF = pb.w >> 16;
    const float4* z4 = (const float4*)zin;
    float4 v0 = z4[((size_t)r0 << 2) + c];   // sentinel n -> zero row, exact +0
    float4 v1 = z4[((size_t)r1 << 2) + c];
    float4 v2 = z4[((size_t)r2 << 2) + c];
    float4 v3 = z4[((size_t)r3 << 2) + c];
    float4 v4 = z4[((size_t)r4 << 2) + c];
    float4 v5 = z4[((size_t)r5 << 2) + c];
    float4 v6 = z4[((size_t)r6 << 2) + c];
    float4 v7 = z4[((size_t)r7 << 2) + c];
    float4 v8 = z4[((size_t)r8 << 2) + c];
    float4 v9 = z4[((size_t)r9 << 2) + c];
    float4 vA = z4[((size_t)rA << 2) + c];
    float4 vB = z4[((size_t)rB << 2) + c];
    float4 vC = z4[((size_t)rC << 2) + c];
    float4 vD = z4[((size_t)rD << 2) + c];
    float4 vE = z4[((size_t)rE << 2) + c];
    float4 vF = z4[((size_t)rF << 2) + c];
    float ax = (((v0.x + v1.x) + (v2.x + v3.x)) + ((v4.x + v5.x) + (v6.x + v7.x)))
             + (((v8.x + v9.x) + (vA.x + vB.x)) + ((vC.x + vD.x) + (vE.x + vF.x)));
    float ay = (((v0.y + v1.y) + (v2.y + v3.y)) + ((v4.y + v5.y) + (v6.y + v7.y)))
             + (((v8.y + v9.y) + (vA.y + vB.y)) + ((vC.y + vD.y) + (vE.y + vF.y)));
    float az = (((v0.z + v1.z) + (v2.z + v3.z)) + ((v4.z + v5.z) + (v6.z + v7.z)))
             + (((v8.z + v9.z) + (vA.z + vB.z)) + ((vC.z + vD.z) + (vE.z + vF.z)));
    float aw = (((v0.w + v1.w) + (v2.w + v3.w)) + ((v4.w + v5.w) + (v6.w + v7.w)))
             + (((v8.w + v9.w) + (vA.w + vB.w)) + ((vC.w + vD.w) + (vE.w + vF.w)));
    if (degi > CAPN) {                    // rare tail via dense csr (4 slots)
        int2 r = be[node];
        for (int q = r.x + t; q < r.y; q += 4) {
            float4 v = z4[(size_t)csr[q] + c];
            ax += v.x; ay += v.y; az += v.z; aw += v.w;
        }
    }
    // reduce over 4 slot-groups within this 16-lane quarter
    #pragma unroll
    for (int off = 8; off >= 4; off >>= 1) {
        ax += __shfl_down(ax, off, 16);
        ay += __shfl_down(ay, off, 16);
        az += __shfl_down(az, off, 16);
        aw += __shfl_down(aw, off, 16);
    }
    if (l16 < 4) {
        float inv = 1.f / (float)(degi > 0 ? degi : 1);
        ((float4*)(zout + (size_t)node * 16))[l16] =
            make_float4(ax * inv, ay * inv, az * inv, aw * inv);
    }
}

// final: logits += field(z7, M7); softmax; thread-per-node
__global__ __launch_bounds__(256) void fieldsoft_k(
    const float* __restrict__ z, float* __restrict__ logits,
    const float* __restrict__ w2, const float* __restrict__ b1,
    const float* __restrict__ b2, const float* __restrict__ M, int n) {
    __shared__ float sw2[256], sM[128], sb1[16], sb2[16];
    int tid = threadIdx.x;
    sw2[tid] = w2[tid];
    if (tid < 128) sM[tid] = M[tid];
    if (tid < 16) { sb1[tid] = b1[tid]; sb2[tid] = b2[tid]; }
    __syncthreads();
    int nid = blockIdx.x * 256 + tid;
    if (nid >= n) return;
    float h[16];
    const float4* zp = (const float4*)(z + (size_t)nid * 16);
    #pragma unroll
    for (int q = 0; q < 4; q++) {
        float4 v = zp[q];
        h[4 * q] = v.x; h[4 * q + 1] = v.y; h[4 * q + 2] = v.z; h[4 * q + 3] = v.w;
    }
    #pragma unroll
    for (int i = 0; i < 16; i++) h[i] = fmaxf(h[i] + sb1[i], 0.f);
    float t2[16];
    #pragma unroll
    for (int j = 0; j < 16; j++) {
        float a = sb2[j];
        #pragma unroll
        for (int i = 0; i < 16; i++) a += h[i] * sw2[i * 16 + j];
        t2[j] = fmaxf(a, 0.f);
    }
    float4* lp4 = (float4*)(logits + (size_t)nid * 8);
    float4 l0 = lp4[0], l1 = lp4[1];
    float v[8] = {l0.x, l0.y, l0.z, l0.w, l1.x, l1.y, l1.z, l1.w};
    #pragma unroll
    for (int j = 0; j < 8; j++) {
        float l = 0.f;
        #pragma unroll
        for (int i = 0; i < 16; i++) l += t2[i] * sM[i * 8 + j];
        v[j] += l;
    }
    float m = v[0];
    #pragma unroll
    for (int j = 1; j < 8; j++) m = fmaxf(m, v[j]);
    float s = 0.f;
    #pragma unroll
    for (int j = 0; j < 8; j++) { v[j] = expf(v[j] - m); s += v[j]; }
    float inv = 1.f / s;
    lp4[0] = make_float4(v[0] * inv, v[1] * inv, v[2] * inv, v[3] * inv);
    lp4[1] = make_float4(v[4] * inv, v[5] * inv, v[6] * inv, v[7] * inv);
}

extern "C" void kernel_launch(void* const* d_in, const int* in_sizes, int n_in,
                              void* d_out, int out_size, void* d_ws, size_t ws_size,
                              hipStream_t stream) {
    const float* x    = (const float*)d_in[0];
    const int*   ei   = (const int*)d_in[1];
    const float* w1   = (const float*)d_in[2];
    const float* b1   = (const float*)d_in[3];
    const float* w2   = (const float*)d_in[4];
    const float* b2   = (const float*)d_in[5];
    const float* w3   = (const float*)d_in[6];
    const float* b3   = (const float*)d_in[7];
    const float* fc1w = (const float*)d_in[8];
    const float* fc1b = (const float*)d_in[9];
    const float* fc2w = (const float*)d_in[10];
    const float* fc2b = (const float*)d_in[11];
    float* out = (float*)d_out;

    int n = in_sizes[0] / 64;
    int E = in_sizes[1] / 2;
    int NB = (n + 127) >> 7;   // 391 for n=50000; NB <= NB2MAX
    const int* src = ei;
    const int* dst = ei + E;

    char* ws = (char*)d_ws;
    auto carve = [&](size_t bytes) {
        char* p = ws;
        ws += (bytes + 255) & ~((size_t)255);
        return p;
    };
    int*   gcur    = (int*)carve((size_t)NB * 4);
    int*   ovbuf   = (int*)carve((size_t)NB * OVCAP * 4);
    int*   binsbuf = (int*)carve((size_t)NB * NBLK * CAPC * 4);
    int*   cnts    = (int*)carve((size_t)NBLK * NB * 4);
    unsigned short* csrp = (unsigned short*)carve((size_t)n * CAPN * 2);
    int*   degs    = (int*)carve((size_t)n * 4);
    int*   csr     = (int*)carve((size_t)NB * CAPB * 4);
    int2*  be      = (int2*)carve((size_t)n * 8);
    float* buf0    = (float*)carve((size_t)(n + 1) * 16 * 4);  // +1 zero row
    float* buf1    = (float*)carve((size_t)(n + 1) * 16 * 4);
    float* M       = (float*)carve(1024 * 4);
    float* cvec    = (float*)carve(8 * 4);
    float* W31     = (float*)carve(256 * 4);
    float* c31     = (float*)carve(16 * 4);

    hipMemsetAsync(gcur, 0, (size_t)NB * 4, stream);
    binfill_k<<<NBLK + 9, 1024, 0, stream>>>(src, dst, E, n, gcur, ovbuf, binsbuf, cnts,
                                             w1, w3, b3, fc1w, fc1b, fc2w, fc2b,
                                             M, cvec, W31, c31);

    int FB = (n + 255) / 256;     // field/proj blocks
    int AB = (n + 15) / 16;       // agg blocks (4 nodes/wave, 4 waves/block)
    csr2_k<<<NB, 256, 0, stream>>>(binsbuf, cnts, gcur, ovbuf, csrp, degs, csr, be, n);
    proj_k<<<FB, 256, 0, stream>>>(x, buf0, buf1, out, w1, b1, w2, b2,
                                   W31, c31, M, cvec, n);

    float* cur = buf0;
    float* nxt = buf1;
    // hop 1: agg only (field0 applied in proj)
    hop_k<<<AB, 256, 0, stream>>>(cur, nxt, out, csrp, degs, be, csr,
                                  w2, b1, b2, M, n, 0);
    { float* t = cur; cur = nxt; nxt = t; }
    // hops 2..7: field(z_k, M_k) + agg(z_k -> z_{k+1}) in one launch
    for (int k = 1; k <= 6; k++) {
        hop_k<<<FB + AB, 256, 0, stream>>>(cur, nxt, out, csrp, degs, be, csr,
                                           w2, b1, b2, M + k * 128, n, FB);
        float* t = cur; cur = nxt; nxt = t;
    }
    // final: field(z7, M7) + softmax
    fieldsoft_k<<<FB, 256, 0, stream>>>(cur, out, w2, b1, b2, M + 7 * 128, n);
}

// Round 20
// 253.013 us; speedup vs baseline: 1.2703x; 1.2703x over previous
//
#include <hip/hip_runtime.h>

// ---------------------------------------------------------------------------
// LinearAggActor R19 (= exact R16 config, session best 253us):
//  - math (verified R2-R16): z0 = t2@(w3@w1)+b3@w1 (16-dim); z_k = A^k z0;
//    logits = cvec + sum_k relu(relu(z_k+b1)@w2+b2) @ M_k ; softmax.
//  - proj_k MUST carry __launch_bounds__(256) single-arg (3-point measured):
//      __launch_bounds__(256)    -> VGPR 256, no spill, ~50us  [R16]
//      __launch_bounds__(256,4)  -> VGPR 64, 104MB spill, 88-145us [R17]
//      no bounds (1024 assumed)  -> VGPR 64, 107MB spill, 92-160us [R18]
//  - R16 (verified): hop agg = 4 nodes/wave, two uint4 -> 16 float4 gathers
//    in flight; csrp permutation pos=((j&3)<<4)|(j>>2).
//  - build (R10-15): binfill multisplit + setup on idle CUs; csr2 low-VGPR
//    -> permuted padded ushort csrp + degs (+dense tail); sentinel row n.
// ---------------------------------------------------------------------------

#define NB2MAX 400   // bins of 128 dsts: supports n <= 51200
#define NBLK   256   // binfill blocks
#define CAP2   32    // LDS staging per bin
#define CAPC   48    // per-(bin,block) cell capacity (mean 16, +8 sigma)
#define CAPB   6144  // per-bin dense CSR region (overflow tails only)
#define OVCAP  1024  // per-bin overflow region (statistically unused)
#define LCAP   6144  // csr2 per-bin LDS capacity (mean 4096, +32 sigma)
#define CAPN   64    // padded slots per node (mean 32, +5.7 sigma)

// blocks [0,NBLK): multisplit into private (bin,block) cells; packed
// (dloc<<16|src); LDS cursors; no global atomics on the hot path.
// blocks [NBLK, NBLK+9): setup role (R10-verified).
__global__ __launch_bounds__(1024) void binfill_k(
    const int* __restrict__ src, const int* __restrict__ dst, int E, int n,
    int* __restrict__ gcur, int* __restrict__ ovbuf,
    int* __restrict__ bins, int* __restrict__ cnts,
    const float* __restrict__ w1, const float* __restrict__ w3,
    const float* __restrict__ b3, const float* __restrict__ fc1w,
    const float* __restrict__ fc1b, const float* __restrict__ fc2w,
    const float* __restrict__ fc2b,
    float* __restrict__ M, float* __restrict__ cvec,
    float* __restrict__ W31, float* __restrict__ c31) {
    __shared__ int lbuf[NB2MAX * CAP2];
    __shared__ int lcnt[NB2MAX];
    __shared__ int lflush[NB2MAX];
    int tid = threadIdx.x;
    int NB = (n + 127) >> 7;

    if ((int)blockIdx.x >= NBLK) {
        // ---------------- setup role ----------------
        float* fl = (float*)lbuf;   // LDS reuse
        int s = (int)blockIdx.x - NBLK;
        if (s == 0) {
            if (tid < 256) {
                int i = tid >> 4, j = tid & 15;
                float a = 0.f;
                for (int g = 0; g < 64; g++) a += w3[i * 64 + g] * w1[g * 16 + j];
                W31[tid] = a;
            } else if (tid < 272) {
                int j = tid - 256;
                float a = 0.f;
                for (int g = 0; g < 64; g++) a += b3[g] * w1[g * 16 + j];
                c31[j] = a;
            } else if (tid >= 320 && tid < 384) {
                int h = tid - 320;
                float a = 0.f;
                for (int r = 0; r < 512; r++) a += b3[r & 63] * fc1w[r * 64 + h];
                fl[h] = a;   // u[h]
            }
            __syncthreads();
            if (tid < 8) {
                float a = fc2b[tid];
                for (int h = 0; h < 64; h++) a += (fc1b[h] + fl[h]) * fc2w[h * 8 + tid];
                cvec[tid] = a;
            }
        } else {
            int k = s - 1;
            {   // Q_k: one elem per thread
                int i = tid >> 6, h = tid & 63;
                float a = 0.f;
                const float* f1 = fc1w + (size_t)(k * 64) * 64 + h;
                for (int g = 0; g < 64; g++) a += w3[i * 64 + g] * f1[g * 64];
                fl[i * 64 + h] = a;
            }
            __syncthreads();
            if (tid < 128) {
                int i = tid >> 3, j = tid & 7;
                float a = 0.f;
                for (int h = 0; h < 64; h++) a += fl[i * 64 + h] * fc2w[h * 8 + j];
                M[k * 128 + i * 8 + j] = a;
            }
        }
        return;
    }

    // ---------------- binfill role ----------------
    for (int b = tid; b < NB; b += 1024) { lcnt[b] = 0; lflush[b] = 0; }
    __syncthreads();
    int blk = blockIdx.x;
    int chunk = (E + NBLK - 1) / NBLK;
    int beg = blk * chunk;
    int end = beg + chunk; if (end > E) end = E;
    for (int t0 = beg; t0 < end; t0 += 1024) {
        int e = t0 + tid;
        if (e < end) {
            int d = dst[e], s = src[e];
            if ((unsigned)d < (unsigned)n && (unsigned)s < (unsigned)n) {
                int b = d >> 7;
                int pk = ((d & 127) << 16) | s;
                int pos = atomicAdd(&lcnt[b], 1);
                if (pos < CAP2) lbuf[b * CAP2 + pos] = pk;
                else {  // statistically never
                    int p = atomicAdd(&gcur[b], 1);
                    if (p < OVCAP) ovbuf[b * OVCAP + p] = pk;
                }
            }
        }
        __syncthreads();
        for (int b = tid; b < NB; b += 1024) {
            int cnt = lcnt[b]; if (cnt > CAP2) cnt = CAP2;
            int fl2 = lflush[b];
            size_t cell = ((size_t)b * NBLK + blk) * CAPC;
            int base = 0;
            while (cnt - base >= 16) {
                if (fl2 + 16 <= CAPC) {
                    int* dp = bins + cell + fl2;
                    #pragma unroll
                    for (int q = 0; q < 16; q++) dp[q] = lbuf[b * CAP2 + base + q];
                    fl2 += 16;
                } else {  // cell overflow (statistically never)
                    int p = atomicAdd(&gcur[b], 16);
                    for (int q = 0; q < 16; q++)
                        if (p + q < OVCAP) ovbuf[b * OVCAP + p + q] = lbuf[b * CAP2 + base + q];
                }
                base += 16;
            }
            int rem = cnt - base;
            if (base > 0)
                for (int q = 0; q < rem; q++) lbuf[b * CAP2 + q] = lbuf[b * CAP2 + base + q];
            lcnt[b] = rem; lflush[b] = fl2;
        }
        __syncthreads();
    }
    for (int b = tid; b < NB; b += 1024) {
        int cnt = lcnt[b]; if (cnt > CAP2) cnt = CAP2;
        int fl2 = lflush[b];
        size_t cell = ((size_t)b * NBLK + blk) * CAPC;
        if (fl2 + cnt <= CAPC) {
            for (int q = 0; q < cnt; q++) bins[cell + fl2 + q] = lbuf[b * CAP2 + q];
            fl2 += cnt;
        } else {
            int p = atomicAdd(&gcur[b], cnt);
            for (int q = 0; q < cnt; q++)
                if (p + q < OVCAP) ovbuf[b * OVCAP + p + q] = lbuf[b * CAP2 + q];
        }
        cnts[(size_t)blk * NB + b] = fl2;
    }
}

// per-bin counting sort -> permuted padded USHORT csrp + degs (+ dense tail
// csr/be for deg>64). One WG per bin; int-only, low VGPR.
// csrp permutation: sorted slot j -> pos ((j&3)<<4)|(j>>2): hop thread t
// owns slots {t, 4+t, ..., 60+t} = 16 contiguous ushorts = two uint4 loads.
__global__ __launch_bounds__(256) void csr2_k(
    const int* __restrict__ bins, const int* __restrict__ cnts,
    const int* __restrict__ gcur, const int* __restrict__ ovbuf,
    unsigned short* __restrict__ csrp, int* __restrict__ degs,
    int* __restrict__ csr, int2* __restrict__ be, int n) {
    __shared__ int hist[128], pref[128], cur[128];
    __shared__ int scnt[NBLK];
    __shared__ int lbuf[LCAP];
    __shared__ int sov;
    int tid = threadIdx.x;
    int NB = (n + 127) >> 7;
    int b = blockIdx.x;
    if (tid < 128) { hist[tid] = 0; cur[tid] = 0; }
    scnt[tid] = cnts[(size_t)tid * NB + b];
    if (tid == 0) {
        int g = gcur[b];
        sov = g < 0 ? 0 : (g > OVCAP ? OVCAP : g);
    }
    __syncthreads();
    {   // pass 1: histogram of dst-local
        int c = scnt[tid];
        size_t cell = ((size_t)b * NBLK + tid) * CAPC;
        for (int i = 0; i < c; i++) atomicAdd(&hist[bins[cell + i] >> 16], 1);
    }
    if (tid == 0)
        for (int i = 0; i < sov; i++) atomicAdd(&hist[ovbuf[b * OVCAP + i] >> 16], 1);
    __syncthreads();
    if (tid == 0) {
        int r = 0;
        for (int i = 0; i < 128; i++) { pref[i] = r; r += hist[i]; }
    }
    __syncthreads();
    {   // pass 2: place into LDS (bin-locally dense, sorted by dst)
        int c = scnt[tid];
        size_t cell = ((size_t)b * NBLK + tid) * CAPC;
        for (int i = 0; i < c; i++) {
            int pk = bins[cell + i];
            int dl = pk >> 16;
            int pos = pref[dl] + atomicAdd(&cur[dl], 1);
            if (pos < LCAP) lbuf[pos] = pk & 0xffff;
        }
    }
    if (tid == 0) {
        for (int i = 0; i < sov; i++) {
            int pk = ovbuf[b * OVCAP + i];
            int dl = pk >> 16;
            int pos = pref[dl] + atomicAdd(&cur[dl], 1);
            if (pos < LCAP) lbuf[pos] = pk & 0xffff;
        }
    }
    __syncthreads();
    // permuted padded ushort CSR; sentinel = n (zero row of z).
    for (int q = tid; q < 128 * CAPN; q += 256) {
        int dl = q >> 6, j = q & 63;
        int d = (b << 7) + dl;
        if (d >= n) break;
        int cnt = hist[dl];
        int v = (j < cnt) ? lbuf[pref[dl] + j] : n;
        int pos = ((j & 3) << 4) | (j >> 2);
        csrp[(size_t)d * CAPN + pos] = (unsigned short)v;
    }
    if (tid < 128) {
        int d = (b << 7) + tid;
        if (d < n) {
            int cnt = hist[tid];
            degs[d] = cnt;
            if (cnt > CAPN) {   // rare tail -> dense region + be (premult x4)
                int s0 = b * CAPB + pref[tid];
                be[d] = make_int2(s0 + CAPN, s0 + cnt);
                for (int j = CAPN; j < cnt; j++)
                    csr[s0 + j] = lbuf[pref[tid] + j] << 2;
            }
        }
    }
}

// proj (streamed x -> z0) + field0 (logits = cvec + f0); zero sentinel rows.
// __launch_bounds__(256) single-arg is REQUIRED (see header 3-point data).
__global__ __launch_bounds__(256) void proj_k(
    const float* __restrict__ x, float* __restrict__ z0, float* __restrict__ z1,
    float* __restrict__ logits,
    const float* __restrict__ w1, const float* __restrict__ b1,
    const float* __restrict__ w2, const float* __restrict__ b2,
    const float* __restrict__ W31, const float* __restrict__ c31,
    const float* __restrict__ M0, const float* __restrict__ cvec, int n) {
    __shared__ float sw1[1024], sw2[256], sW[256], sM[128];
    __shared__ float sb1[16], sb2[16], sc[16], scv[8];
    int tid = threadIdx.x;
    for (int i = tid; i < 1024; i += 256) sw1[i] = w1[i];
    sw2[tid] = w2[tid & 255];
    sW[tid & 255] = W31[tid & 255];
    if (tid < 128) sM[tid] = M0[tid];
    if (tid < 16) { sb1[tid] = b1[tid]; sb2[tid] = b2[tid]; sc[tid] = c31[tid]; }
    if (tid < 8) scv[tid] = cvec[tid];
    __syncthreads();
    if (blockIdx.x == 0 && tid < 16) {   // zero sentinel row n of both bufs
        z0[(size_t)n * 16 + tid] = 0.f;
        z1[(size_t)n * 16 + tid] = 0.f;
    }
    int nid = blockIdx.x * 256 + tid;
    if (nid >= n) return;
    float t1[16];
    #pragma unroll
    for (int j = 0; j < 16; j++) t1[j] = sb1[j];
    const float4* xp = (const float4*)(x + (size_t)nid * 64);
    #pragma unroll
    for (int q = 0; q < 16; q++) {
        float4 v = xp[q];
        #pragma unroll
        for (int j = 0; j < 16; j++)
            t1[j] += v.x * sw1[(4 * q) * 16 + j] + v.y * sw1[(4 * q + 1) * 16 + j]
                   + v.z * sw1[(4 * q + 2) * 16 + j] + v.w * sw1[(4 * q + 3) * 16 + j];
    }
    #pragma unroll
    for (int j = 0; j < 16; j++) t1[j] = fmaxf(t1[j], 0.f);
    float t2[16];
    #pragma unroll
    for (int j = 0; j < 16; j++) {
        float a = sb2[j];
        #pragma unroll
        for (int i = 0; i < 16; i++) a += t1[i] * sw2[i * 16 + j];
        t2[j] = fmaxf(a, 0.f);
    }
    float z[16];
    #pragma unroll
    for (int j = 0; j < 16; j++) {
        float a = sc[j];
        #pragma unroll
        for (int i = 0; i < 16; i++) a += t2[i] * sW[i * 16 + j];
        z[j] = a;
    }
    float4* zo = (float4*)(z0 + (size_t)nid * 16);
    #pragma unroll
    for (int q = 0; q < 4; q++)
        zo[q] = make_float4(z[4 * q], z[4 * q + 1], z[4 * q + 2], z[4 * q + 3]);
    float h[16], f2[16];
    #pragma unroll
    for (int i = 0; i < 16; i++) h[i] = fmaxf(z[i] + sb1[i], 0.f);
    #pragma unroll
    for (int j = 0; j < 16; j++) {
        float a = sb2[j];
        #pragma unroll
        for (int i = 0; i < 16; i++) a += h[i] * sw2[i * 16 + j];
        f2[j] = fmaxf(a, 0.f);
    }
    float* lp = logits + (size_t)nid * 8;
    #pragma unroll
    for (int j = 0; j < 8; j++) {
        float l = scv[j];
        #pragma unroll
        for (int i = 0; i < 16; i++) l += f2[i] * sM[i * 8 + j];
        lp[j] = l;
    }
}

// One launch per hop. Blocks [0,FB): field(z_k) thread-per-node;
// blocks [FB,..): agg, 4 nodes/wave (16 lanes each = 4 slot-groups x 4 chans),
// two uint4 -> 16 round-indices -> 16 float4 gathers in flight per thread.
__global__ __launch_bounds__(256, 4) void hop_k(
    const float* __restrict__ zin, float* __restrict__ zout, float* __restrict__ logits,
    const unsigned short* __restrict__ csrp, const int* __restrict__ degs,
    const int2* __restrict__ be, const int* __restrict__ csr,
    const float* __restrict__ w2, const float* __restrict__ b1,
    const float* __restrict__ b2, const float* __restrict__ M, int n, int FB) {
    __shared__ float sw2[256], sM[128], sb1[16], sb2[16];
    int tid = threadIdx.x;
    if ((int)blockIdx.x < FB) {
        // ---- field role ----
        sw2[tid] = w2[tid];
        if (tid < 128) sM[tid] = M[tid];
        if (tid < 16) { sb1[tid] = b1[tid]; sb2[tid] = b2[tid]; }
        __syncthreads();
        int nid = blockIdx.x * 256 + tid;
        if (nid >= n) return;
        float h[16];
        const float4* zp = (const float4*)(zin + (size_t)nid * 16);
        #pragma unroll
        for (int q = 0; q < 4; q++) {
            float4 v = zp[q];
            h[4 * q] = v.x; h[4 * q + 1] = v.y; h[4 * q + 2] = v.z; h[4 * q + 3] = v.w;
        }
        #pragma unroll
        for (int i = 0; i < 16; i++) h[i] = fmaxf(h[i] + sb1[i], 0.f);
        float t2[16];
        #pragma unroll
        for (int j = 0; j < 16; j++) {
            float a = sb2[j];
            #pragma unroll
            for (int i = 0; i < 16; i++) a += h[i] * sw2[i * 16 + j];
            t2[j] = fmaxf(a, 0.f);
        }
        float* lp = logits + (size_t)nid * 8;
        #pragma unroll
        for (int j = 0; j < 8; j++) {
            float l = 0.f;
            #pragma unroll
            for (int i = 0; i < 16; i++) l += t2[i] * sM[i * 8 + j];
            lp[j] += l;
        }
        return;
    }
    // ---- agg role: 4 nodes per wave ----
    int wave = tid >> 6;
    int lane = tid & 63;
    int quarter = lane >> 4;              // which node of the 4
    int l16 = lane & 15;
    int t = l16 >> 2, c = l16 & 3;        // slot-group 0..3, channel 0..3
    int node = (((int)blockIdx.x - FB) * 4 + wave) * 4 + quarter;
    if (node >= n) return;
    int degi = degs[node];                // independent load, hidden
    // two 16B loads = 16 round-indices for this thread's slot-group
    const uint4* ip = (const uint4*)(csrp + ((size_t)node << 6));
    uint4 pa = ip[t * 2];
    uint4 pb = ip[t * 2 + 1];
    int r0 = pa.x & 0xffff, r1 = pa.x >> 16;
    int r2 = pa.y & 0xffff, r3 = pa.y >> 16;
    int r4 = pa.z & 0xffff, r5 = pa.z >> 16;
    int r6 = pa.w & 0xffff, r7 = pa.w >> 16;
    int r8 = pb.x & 0xffff, r9 = pb.x >> 16;
    int rA = pb.y & 0xffff, rB = pb.y >> 16;
    int rC = pb.z & 0xffff, rD = pb.z >> 16;
    int rE = pb.w & 0xffff, rF = pb.w >> 16;
    const float4* z4 = (const float4*)zin;
    float4 v0 = z4[((size_t)r0 << 2) + c];   // sentinel n -> zero row, exact +0
    float4 v1 = z4[((size_t)r1 << 2) + c];
    float4 v2 = z4[((size_t)r2 << 2) + c];
    float4 v3 = z4[((size_t)r3 << 2) + c];
    float4 v4 = z4[((size_t)r4 << 2) + c];
    float4 v5 = z4[((size_t)r5 << 2) + c];
    float4 v6 = z4[((size_t)r6 << 2) + c];
    float4 v7 = z4[((size_t)r7 << 2) + c];
    float4 v8 = z4[((size_t)r8 << 2) + c];
    float4 v9 = z4[((size_t)r9 << 2) + c];
    float4 vA = z4[((size_t)rA << 2) + c];
    float4 vB = z4[((size_t)rB << 2) + c];
    float4 vC = z4[((size_t)rC << 2) + c];
    float4 vD = z4[((size_t)rD << 2) + c];
    float4 vE = z4[((size_t)rE << 2) + c];
    float4 vF = z4[((size_t)rF << 2) + c];
    float ax = (((v0.x + v1.x) + (v2.x + v3.x)) + ((v4.x + v5.x) + (v6.x + v7.x)))
             + (((v8.x + v9.x) + (vA.x + vB.x)) + ((vC.x + vD.x) + (vE.x + vF.x)));
    float ay = (((v0.y + v1.y) + (v2.y + v3.y)) + ((v4.y + v5.y) + (v6.y + v7.y)))
             + (((v8.y + v9.y) + (vA.y + vB.y)) + ((vC.y + vD.y) + (vE.y + vF.y)));
    float az = (((v0.z + v1.z) + (v2.z + v3.z)) + ((v4.z + v5.z) + (v6.z + v7.z)))
             + (((v8.z + v9.z) + (vA.z + vB.z)) + ((vC.z + vD.z) + (vE.z + vF.z)));
    float aw = (((v0.w + v1.w) + (v2.w + v3.w)) + ((v4.w + v5.w) + (v6.w + v7.w)))
             + (((v8.w + v9.w) + (vA.w + vB.w)) + ((vC.w + vD.w) + (vE.w + vF.w)));
    if (degi > CAPN) {                    // rare tail via dense csr (4 slots)
        int2 r = be[node];
        for (int q = r.x + t; q < r.y; q += 4) {
            float4 v = z4[(size_t)csr[q] + c];
            ax += v.x; ay += v.y; az += v.z; aw += v.w;
        }
    }
    // reduce over 4 slot-groups within this 16-lane quarter
    #pragma unroll
    for (int off = 8; off >= 4; off >>= 1) {
        ax += __shfl_down(ax, off, 16);
        ay += __shfl_down(ay, off, 16);
        az += __shfl_down(az, off, 16);
        aw += __shfl_down(aw, off, 16);
    }
    if (l16 < 4) {
        float inv = 1.f / (float)(degi > 0 ? degi : 1);
        ((float4*)(zout + (size_t)node * 16))[l16] =
            make_float4(ax * inv, ay * inv, az * inv, aw * inv);
    }
}

// final: logits += field(z7, M7); softmax; thread-per-node
__global__ __launch_bounds__(256) void fieldsoft_k(
    const float* __restrict__ z, float* __restrict__ logits,
    const float* __restrict__ w2, const float* __restrict__ b1,
    const float* __restrict__ b2, const float* __restrict__ M, int n) {
    __shared__ float sw2[256], sM[128], sb1[16], sb2[16];
    int tid = threadIdx.x;
    sw2[tid] = w2[tid];
    if (tid < 128) sM[tid] = M[tid];
    if (tid < 16) { sb1[tid] = b1[tid]; sb2[tid] = b2[tid]; }
    __syncthreads();
    int nid = blockIdx.x * 256 + tid;
    if (nid >= n) return;
    float h[16];
    const float4* zp = (const float4*)(z + (size_t)nid * 16);
    #pragma unroll
    for (int q = 0; q < 4; q++) {
        float4 v = zp[q];
        h[4 * q] = v.x; h[4 * q + 1] = v.y; h[4 * q + 2] = v.z; h[4 * q + 3] = v.w;
    }
    #pragma unroll
    for (int i = 0; i < 16; i++) h[i] = fmaxf(h[i] + sb1[i], 0.f);
    float t2[16];
    #pragma unroll
    for (int j = 0; j < 16; j++) {
        float a = sb2[j];
        #pragma unroll
        for (int i = 0; i < 16; i++) a += h[i] * sw2[i * 16 + j];
        t2[j] = fmaxf(a, 0.f);
    }
    float4* lp4 = (float4*)(logits + (size_t)nid * 8);
    float4 l0 = lp4[0], l1 = lp4[1];
    float v[8] = {l0.x, l0.y, l0.z, l0.w, l1.x, l1.y, l1.z, l1.w};
    #pragma unroll
    for (int j = 0; j < 8; j++) {
        float l = 0.f;
        #pragma unroll
        for (int i = 0; i < 16; i++) l += t2[i] * sM[i * 8 + j];
        v[j] += l;
    }
    float m = v[0];
    #pragma unroll
    for (int j = 1; j < 8; j++) m = fmaxf(m, v[j]);
    float s = 0.f;
    #pragma unroll
    for (int j = 0; j < 8; j++) { v[j] = expf(v[j] - m); s += v[j]; }
    float inv = 1.f / s;
    lp4[0] = make_float4(v[0] * inv, v[1] * inv, v[2] * inv, v[3] * inv);
    lp4[1] = make_float4(v[4] * inv, v[5] * inv, v[6] * inv, v[7] * inv);
}

extern "C" void kernel_launch(void* const* d_in, const int* in_sizes, int n_in,
                              void* d_out, int out_size, void* d_ws, size_t ws_size,
                              hipStream_t stream) {
    const float* x    = (const float*)d_in[0];
    const int*   ei   = (const int*)d_in[1];
    const float* w1   = (const float*)d_in[2];
    const float* b1   = (const float*)d_in[3];
    const float* w2   = (const float*)d_in[4];
    const float* b2   = (const float*)d_in[5];
    const float* w3   = (const float*)d_in[6];
    const float* b3   = (const float*)d_in[7];
    const float* fc1w = (const float*)d_in[8];
    const float* fc1b = (const float*)d_in[9];
    const float* fc2w = (const float*)d_in[10];
    const float* fc2b = (const float*)d_in[11];
    float* out = (float*)d_out;

    int n = in_sizes[0] / 64;
    int E = in_sizes[1] / 2;
    int NB = (n + 127) >> 7;   // 391 for n=50000; NB <= NB2MAX
    const int* src = ei;
    const int* dst = ei + E;

    char* ws = (char*)d_ws;
    auto carve = [&](size_t bytes) {
        char* p = ws;
        ws += (bytes + 255) & ~((size_t)255);
        return p;
    };
    int*   gcur    = (int*)carve((size_t)NB * 4);
    int*   ovbuf   = (int*)carve((size_t)NB * OVCAP * 4);
    int*   binsbuf = (int*)carve((size_t)NB * NBLK * CAPC * 4);
    int*   cnts    = (int*)carve((size_t)NBLK * NB * 4);
    unsigned short* csrp = (unsigned short*)carve((size_t)n * CAPN * 2);
    int*   degs    = (int*)carve((size_t)n * 4);
    int*   csr     = (int*)carve((size_t)NB * CAPB * 4);
    int2*  be      = (int2*)carve((size_t)n * 8);
    float* buf0    = (float*)carve((size_t)(n + 1) * 16 * 4);  // +1 zero row
    float* buf1    = (float*)carve((size_t)(n + 1) * 16 * 4);
    float* M       = (float*)carve(1024 * 4);
    float* cvec    = (float*)carve(8 * 4);
    float* W31     = (float*)carve(256 * 4);
    float* c31     = (float*)carve(16 * 4);

    hipMemsetAsync(gcur, 0, (size_t)NB * 4, stream);
    binfill_k<<<NBLK + 9, 1024, 0, stream>>>(src, dst, E, n, gcur, ovbuf, binsbuf, cnts,
                                             w1, w3, b3, fc1w, fc1b, fc2w, fc2b,
                                             M, cvec, W31, c31);

    int FB = (n + 255) / 256;     // field/proj blocks
    int AB = (n + 15) / 16;       // agg blocks (4 nodes/wave, 4 waves/block)
    csr2_k<<<NB, 256, 0, stream>>>(binsbuf, cnts, gcur, ovbuf, csrp, degs, csr, be, n);
    proj_k<<<FB, 256, 0, stream>>>(x, buf0, buf1, out, w1, b1, w2, b2,
                                   W31, c31, M, cvec, n);

    float* cur = buf0;
    float* nxt = buf1;
    // hop 1: agg only (field0 applied in proj)
    hop_k<<<AB, 256, 0, stream>>>(cur, nxt, out, csrp, degs, be, csr,
                                  w2, b1, b2, M, n, 0);
    { float* t = cur; cur = nxt; nxt = t; }
    // hops 2..7: field(z_k, M_k) + agg(z_k -> z_{k+1}) in one launch
    for (int k = 1; k <= 6; k++) {
        hop_k<<<FB + AB, 256, 0, stream>>>(cur, nxt, out, csrp, degs, be, csr,
                                           w2, b1, b2, M + k * 128, n, FB);
        float* t = cur; cur = nxt; nxt = t;
    }
    // final: field(z7, M7) + softmax
    fieldsoft_k<<<FB, 256, 0, stream>>>(cur, out, w2, b1, b2, M + 7 * 128, n);
}